// Round 7
// baseline (785.656 us; speedup 1.0000x reference)
//
#include <hip/hip_runtime.h>
#include <hip/hip_bf16.h>

#define NEGV -1e30f
typedef __attribute__((ext_vector_type(8))) short bf16x8;
typedef __attribute__((ext_vector_type(4))) float f32x4;
typedef __attribute__((ext_vector_type(4))) int i32x4;

__device__ __forceinline__ float sigmoidf_(float x) { return 1.0f / (1.0f + __expf(-x)); }
__device__ __forceinline__ float tanhf_(float x) {
    float ax = fabsf(x);
    float e = __expf(-2.0f * ax);
    float t = (1.0f - e) / (1.0f + e);
    return copysignf(t, x);
}
__device__ __forceinline__ float bf2f(unsigned short u) {
    union { float f; unsigned int i; } x; x.i = ((unsigned int)u) << 16; return x.f;
}

// ---------------------------------------------------------------------------
// wqb_t[h'][d] = sum_k Wbil[k][h'] * Wq[k][d]   (256x256 fp32)
// ---------------------------------------------------------------------------
__global__ __launch_bounds__(256) void wqb_gemm(const float* __restrict__ Wbil_,
    const float* __restrict__ Wq_, float* __restrict__ outw)
{
    __shared__ __align__(16) float As[32 * 68];
    __shared__ __align__(16) float Bs[32 * 68];
    const int tid = threadIdx.x, tx = tid & 15, ty = tid >> 4;
    const int rb = blockIdx.x * 64, cb = blockIdx.y * 64;
    float acc[4][4] = {};
    for (int k0 = 0; k0 < 256; k0 += 32) {
        __syncthreads();
        for (int f = tid; f < 2048; f += 256) {
            int kk = f >> 6, r = f & 63;
            As[kk * 68 + r] = Wbil_[(size_t)(k0 + kk) * 256 + rb + r];
        }
        for (int f = tid; f < 2048; f += 256) {
            int kk = f >> 6, c = f & 63;
            Bs[kk * 68 + c] = Wq_[(size_t)(k0 + kk) * 256 + cb + c];
        }
        __syncthreads();
#pragma unroll
        for (int kk = 0; kk < 32; ++kk) {
            float4 a4 = *(const float4*)(As + kk * 68 + ty * 4);
            float4 b4 = *(const float4*)(Bs + kk * 68 + tx * 4);
            float av[4] = {a4.x, a4.y, a4.z, a4.w};
            float bv[4] = {b4.x, b4.y, b4.z, b4.w};
#pragma unroll
            for (int i = 0; i < 4; ++i)
#pragma unroll
                for (int j = 0; j < 4; ++j) acc[i][j] += av[i] * bv[j];
        }
    }
#pragma unroll
    for (int i = 0; i < 4; ++i)
#pragma unroll
        for (int j = 0; j < 4; ++j)
            outw[(size_t)(rb + ty * 4 + i) * 256 + cb + tx * 4 + j] = acc[i][j];
}

// ---------------------------------------------------------------------------
// One-launch conversion of all weights to bf16 MFMA-B swizzled layout:
// (n,k) -> [((nt*(K/32)+kt)*64 + quad*16 + (n&15))*8 + (k&7)]
// ---------------------------------------------------------------------------
__device__ __forceinline__ void swz_store(const float* __restrict__ src,
    __hip_bfloat16* __restrict__ dst, int idx, int kshift)
{
    int n = idx >> kshift, k = idx & ((1 << kshift) - 1);
    int nt = n >> 4, kt = k >> 5, quad = (k & 31) >> 3, pos = k & 7;
    dst[((size_t)((nt << (kshift - 5)) + kt) * 64 + quad * 16 + (n & 15)) * 8 + pos] =
        (__hip_bfloat16)src[idx];
}

__global__ __launch_bounds__(256) void convert_all(
    const float* __restrict__ Wih_n, const float* __restrict__ Wih_g,
    const float* __restrict__ Whh_n, const float* __restrict__ Whh_g,
    const float* __restrict__ Wk_,   const float* __restrict__ Wv_,
    const float* __restrict__ wqb_f,
    __hip_bfloat16* Wih_n_sw, __hip_bfloat16* Wih_g_sw,
    __hip_bfloat16* Whh_n_sw, __hip_bfloat16* Whh_g_sw,
    __hip_bfloat16* Wk_sw, __hip_bfloat16* Wv_sw, __hip_bfloat16* wqb_sw)
{
    int g = blockIdx.x * 256 + threadIdx.x;
    if (g < 98304)        swz_store(Wih_n, Wih_n_sw, g, 7);
    else if (g < 196608)  swz_store(Wih_g, Wih_g_sw, g - 98304, 7);
    else if (g < 393216)  swz_store(Whh_n, Whh_n_sw, g - 196608, 8);
    else if (g < 589824)  swz_store(Whh_g, Whh_g_sw, g - 393216, 8);
    else if (g < 655360)  swz_store(Wk_,   Wk_sw,   g - 589824, 8);
    else if (g < 720896)  swz_store(Wv_,   Wv_sw,   g - 655360, 8);
    else                  swz_store(wqb_f, wqb_sw,  g - 720896, 8);
}

// ---------------------------------------------------------------------------
// gi = x @ Wih^T + bih, all 768 output cols per block (A staged once).
// ---------------------------------------------------------------------------
__global__ __launch_bounds__(256) void gi_gemm(
    const float* __restrict__ A0, const float* __restrict__ A1,
    const __hip_bfloat16* __restrict__ W0, const __hip_bfloat16* __restrict__ W1,
    const float* __restrict__ b0, const float* __restrict__ b1,
    __hip_bfloat16* __restrict__ C)
{
    __shared__ __align__(16) __hip_bfloat16 As[64 * 136];
    const int tid = threadIdx.x, wave = tid >> 6, lane = tid & 63;
    const int quad = lane >> 4, lr = lane & 15;
    const int rb = blockIdx.x * 64;
    const bool node = rb < 4096;
    const float* A = node ? (A0 + (size_t)rb * 128) : (A1 + (size_t)(rb - 4096) * 128);
    const __hip_bfloat16* W = node ? W0 : W1;
    const float* bias = node ? b0 : b1;

    for (int f = tid; f < 1024; f += 256) {
        int row = f >> 4, cc = (f & 15) * 8;
        const float* Af = A + (size_t)row * 128 + cc;
        float4 v0 = *(const float4*)Af;
        float4 v1 = *(const float4*)(Af + 4);
        __hip_bfloat16* d = As + row * 136 + cc;
        d[0] = (__hip_bfloat16)v0.x; d[1] = (__hip_bfloat16)v0.y;
        d[2] = (__hip_bfloat16)v0.z; d[3] = (__hip_bfloat16)v0.w;
        d[4] = (__hip_bfloat16)v1.x; d[5] = (__hip_bfloat16)v1.y;
        d[6] = (__hip_bfloat16)v1.z; d[7] = (__hip_bfloat16)v1.w;
    }
    __syncthreads();

    bf16x8 afr[4];
#pragma unroll
    for (int kt = 0; kt < 4; ++kt)
        afr[kt] = *(const bf16x8*)(const void*)(As + (wave * 16 + lr) * 136 + kt * 32 + quad * 8);

    const int r0 = rb + wave * 16 + quad * 4;
    for (int ntg = 0; ntg < 48; ++ntg) {
        f32x4 acc = {0.f, 0.f, 0.f, 0.f};
#pragma unroll
        for (int kt = 0; kt < 4; ++kt) {
            bf16x8 bfr = *(const bf16x8*)(const void*)(W + ((size_t)(ntg * 4 + kt) * 64 + lane) * 8);
            acc = __builtin_amdgcn_mfma_f32_16x16x32_bf16(afr[kt], bfr, acc, 0, 0, 0);
        }
        int col = ntg * 16 + lr;
        float bv = bias[col];
#pragma unroll
        for (int rg = 0; rg < 4; ++rg)
            C[(size_t)(r0 + rg) * 768 + col] = (__hip_bfloat16)(acc[rg] + bv);
    }
}

// ---------------------------------------------------------------------------
// Weight-stationary persistent GRU scan, AGPR-pin + intrinsic-MFMA edition.
// 68 blocks x 256 threads (1 wave/SIMD). Wave owns 12 n-tiles = 96 fragments:
// 60 pinned as 240 scalar AGPRs at init (v_accvgpr_write, compiler-placed),
// copied back per use with v_accvgpr_read into normal virtual registers that
// feed the INTRINSIC MFMA (all hazards compiler-managed — the R4-validated
// path). 36 fragments left as loads (hoisted or L2-streamed). Accumulation
// order identical to round 4 => bit-identical numerics expected.
// ---------------------------------------------------------------------------
__global__ __launch_bounds__(256, 1) void scan_kernel(
    const __hip_bfloat16* __restrict__ gi,
    const __hip_bfloat16* __restrict__ Whh_n_sw,
    const __hip_bfloat16* __restrict__ Whh_g_sw,
    const float* __restrict__ bhh_node, const float* __restrict__ bhh_ngh,
    const float* __restrict__ node_hidden, const float* __restrict__ neighbors_hidden,
    __hip_bfloat16* __restrict__ node_out, __hip_bfloat16* __restrict__ ngh_out,
    float* __restrict__ out_node_hT, float* __restrict__ out_ngh_hT)
{
    __shared__ __align__(16) __hip_bfloat16 gh_b[16 * 776];
    __shared__ __align__(16) __hip_bfloat16 h_frag[8 * 64 * 8];
    __shared__ float bhh_l[768];
    const int tid = threadIdx.x;
    const int wave = tid >> 6, lane = tid & 63;
    const int quad = lane >> 4, lr = lane & 15;
    const int row0 = blockIdx.x * 16;
    const bool isnode = (row0 < 64);
    const __hip_bfloat16* Wsw = isnode ? Whh_n_sw : Whh_g_sw;
    const float* bhh = isnode ? bhh_node : bhh_ngh;
    const int pr = tid >> 4;            // 0..15
    const int pc0 = (tid & 15) * 16;    // 0..240
    const int grow = row0 + pr;
    const size_t gibase = isnode ? ((size_t)grow * 64) : (4096 + (size_t)(grow - 64) * 64);
    const int fragoff = ((pc0 >> 5) * 64 + ((pc0 & 31) >> 3) * 16 + pr) * 8;
    __hip_bfloat16* orow_base = isnode
        ? (node_out + ((size_t)grow * 64) * 256 + pc0)
        : (ngh_out + ((size_t)(grow - 64) * 64) * 256 + pc0);

    // ---- pin fragments f=0..59 as 240 scalar AGPRs
    int wa[240];
#pragma unroll
    for (int f = 0; f < 60; ++f) {
        i32x4 t = *(const i32x4*)(const void*)(Wsw + ((size_t)(wave * 96 + f) * 64 + lane) * 8);
        asm volatile("" : "=a"(wa[4 * f + 0]) : "0"(t[0]));
        asm volatile("" : "=a"(wa[4 * f + 1]) : "0"(t[1]));
        asm volatile("" : "=a"(wa[4 * f + 2]) : "0"(t[2]));
        asm volatile("" : "=a"(wa[4 * f + 3]) : "0"(t[3]));
    }

    for (int f = tid; f < 768; f += 256) bhh_l[f] = bhh[f];

    // ---- h0 -> fp32 register master + bf16 fragment LDS
    float hm[16];
    {
        const float* src = isnode ? (node_hidden + (size_t)row0 * 256)
                                  : (neighbors_hidden + (size_t)(row0 - 64) * 256);
        const float* sp = src + (size_t)pr * 256 + pc0;
        __hip_bfloat16 hb[16];
#pragma unroll
        for (int c = 0; c < 4; ++c) {
            float4 v = *(const float4*)(sp + c * 4);
            hm[c * 4 + 0] = v.x; hm[c * 4 + 1] = v.y;
            hm[c * 4 + 2] = v.z; hm[c * 4 + 3] = v.w;
        }
#pragma unroll
        for (int jj = 0; jj < 16; ++jj) hb[jj] = (__hip_bfloat16)hm[jj];
        *(uint4*)(void*)(h_frag + fragoff)       = *(const uint4*)(const void*)hb;
        *(uint4*)(void*)(h_frag + fragoff + 128) = *(const uint4*)(const void*)(hb + 8);
    }
    __syncthreads();

#pragma unroll 1
    for (int t = 0; t < 64; ++t) {
        // gi prefetch (loads issued before the MFMA phase; consumed after barrier)
        const __hip_bfloat16* g = gi + (gibase + t) * 768 + pc0;
        bf16x8 g_r0 = *(const bf16x8*)(const void*)(g);
        bf16x8 g_r1 = *(const bf16x8*)(const void*)(g + 8);
        bf16x8 g_z0 = *(const bf16x8*)(const void*)(g + 256);
        bf16x8 g_z1 = *(const bf16x8*)(const void*)(g + 264);
        bf16x8 g_n0 = *(const bf16x8*)(const void*)(g + 512);
        bf16x8 g_n1 = *(const bf16x8*)(const void*)(g + 520);

        // ---- MFMA: gh = h @ Whh^T (kt-outer, nt-inner — round-4 order)
        f32x4 acc[12];
#pragma unroll
        for (int nt = 0; nt < 12; ++nt) acc[nt] = (f32x4){0.f, 0.f, 0.f, 0.f};
#pragma unroll
        for (int kt = 0; kt < 8; ++kt) {
            bf16x8 afr = *(const bf16x8*)(const void*)(h_frag + (kt * 64 + lane) * 8);
#pragma unroll
            for (int nt = 0; nt < 12; ++nt) {
                const int f = nt * 8 + kt;
                bf16x8 bfr;
                if (f < 60) {
                    union { int u[4]; bf16x8 v; } wb;
                    asm volatile("v_accvgpr_read_b32 %0, %1" : "=v"(wb.u[0]) : "a"(wa[4 * f + 0]));
                    asm volatile("v_accvgpr_read_b32 %0, %1" : "=v"(wb.u[1]) : "a"(wa[4 * f + 1]));
                    asm volatile("v_accvgpr_read_b32 %0, %1" : "=v"(wb.u[2]) : "a"(wa[4 * f + 2]));
                    asm volatile("v_accvgpr_read_b32 %0, %1" : "=v"(wb.u[3]) : "a"(wa[4 * f + 3]));
                    bfr = wb.v;
                } else {
                    bfr = *(const bf16x8*)(const void*)(
                        Wsw + ((size_t)(wave * 96 + f) * 64 + lane) * 8);
                }
                acc[nt] = __builtin_amdgcn_mfma_f32_16x16x32_bf16(afr, bfr, acc[nt], 0, 0, 0);
            }
        }
#pragma unroll
        for (int nt = 0; nt < 12; ++nt) {
            int col = (wave * 12 + nt) * 16 + lr;
#pragma unroll
            for (int rg = 0; rg < 4; ++rg)
                gh_b[(quad * 4 + rg) * 776 + col] = (__hip_bfloat16)acc[nt][rg];
        }
        __syncthreads();

        // ---- pointwise gates: row pr, 16 cols, fp32 master in registers
        {
            const __hip_bfloat16* ghrow = gh_b + pr * 776;
            bf16x8 Gr[2], Gz[2], Gn[2], gr[2], gz[2], gn[2];
            Gr[0] = *(const bf16x8*)(const void*)(ghrow + pc0);
            Gr[1] = *(const bf16x8*)(const void*)(ghrow + pc0 + 8);
            Gz[0] = *(const bf16x8*)(const void*)(ghrow + 256 + pc0);
            Gz[1] = *(const bf16x8*)(const void*)(ghrow + 256 + pc0 + 8);
            Gn[0] = *(const bf16x8*)(const void*)(ghrow + 512 + pc0);
            Gn[1] = *(const bf16x8*)(const void*)(ghrow + 512 + pc0 + 8);
            gr[0] = g_r0; gr[1] = g_r1; gz[0] = g_z0; gz[1] = g_z1;
            gn[0] = g_n0; gn[1] = g_n1;
            __hip_bfloat16 hb[16];
#pragma unroll
            for (int c = 0; c < 2; ++c)
#pragma unroll
                for (int jj = 0; jj < 8; ++jj) {
                    int j = pc0 + c * 8 + jj;
                    int e = c * 8 + jj;
                    float ghr = bf2f((unsigned short)Gr[c][jj]) + bhh_l[j];
                    float ghz = bf2f((unsigned short)Gz[c][jj]) + bhh_l[256 + j];
                    float ghn = bf2f((unsigned short)Gn[c][jj]) + bhh_l[512 + j];
                    float rg_ = sigmoidf_(bf2f((unsigned short)gr[c][jj]) + ghr);
                    float zg  = sigmoidf_(bf2f((unsigned short)gz[c][jj]) + ghz);
                    float ng  = tanhf_(bf2f((unsigned short)gn[c][jj]) + rg_ * ghn);
                    float hn = (1.0f - zg) * ng + zg * hm[e];
                    hm[e] = hn;
                    hb[e] = (__hip_bfloat16)hn;
                }
            *(uint4*)(void*)(h_frag + fragoff)       = *(const uint4*)(const void*)hb;
            *(uint4*)(void*)(h_frag + fragoff + 128) = *(const uint4*)(const void*)(hb + 8);
            __hip_bfloat16* orow = orow_base + (size_t)t * 256;
            *(uint4*)(void*)(orow)     = *(const uint4*)(const void*)hb;
            *(uint4*)(void*)(orow + 8) = *(const uint4*)(const void*)(hb + 8);
        }
        __syncthreads();
    }

    // ---- final hidden states fp32
    {
        float* dst = isnode ? (out_node_hT + (size_t)row0 * 256)
                            : (out_ngh_hT + (size_t)(row0 - 64) * 256);
        float* dp = dst + (size_t)pr * 256 + pc0;
#pragma unroll
        for (int c = 0; c < 4; ++c) {
            float4 v = {hm[c * 4 + 0], hm[c * 4 + 1], hm[c * 4 + 2], hm[c * 4 + 3]};
            *(float4*)(dp + c * 4) = v;
        }
    }
}

// ---------------------------------------------------------------------------
// Fused K/V(+Qb for node rows) GEMM (round-4 validated).
// ---------------------------------------------------------------------------
__global__ __launch_bounds__(256) void kv_gemm(
    const __hip_bfloat16* __restrict__ A0, const __hip_bfloat16* __restrict__ A1,
    const __hip_bfloat16* __restrict__ Wk_sw, const __hip_bfloat16* __restrict__ Wv_sw,
    const __hip_bfloat16* __restrict__ wqb_sw,
    __hip_bfloat16* __restrict__ Kb, __hip_bfloat16* __restrict__ Vt,
    __hip_bfloat16* __restrict__ Qb)
{
    __shared__ __align__(16) __hip_bfloat16 As[64 * 264];
    const int tid = threadIdx.x, wave = tid >> 6, lane = tid & 63;
    const int quad = lane >> 4, lr = lane & 15;
    const int rb = blockIdx.x * 64;
    const bool node = rb < 4096;
    const __hip_bfloat16* A = node ? (A0 + (size_t)rb * 256) : (A1 + (size_t)(rb - 4096) * 256);

    for (int f = tid; f < 2048; f += 256) {
        int row = f >> 5, cc = (f & 31) * 8;
        *(uint4*)(void*)(As + row * 264 + cc) =
            *(const uint4*)(const void*)(A + (size_t)row * 256 + cc);
    }
    __syncthreads();

    bf16x8 afr[8];
#pragma unroll
    for (int kt = 0; kt < 8; ++kt)
        afr[kt] = *(const bf16x8*)(const void*)(As + (wave * 16 + lr) * 264 + kt * 32 + quad * 8);

    int b_, slot;
    if (node) { b_ = rb >> 6; slot = 0; }
    else { int rr = (rb - 4096) >> 6; b_ = rr >> 4; slot = (rr & 15) + 1; }
    const size_t kbase = ((size_t)b_ * 1088 + slot * 64) * 256;
    const size_t vtbase = (size_t)(b_ * 17 + slot) * 256 * 64;
    const int s0 = wave * 16 + quad * 4;

    for (int ntg = 0; ntg < 16; ++ntg) {
        f32x4 acc = {0.f, 0.f, 0.f, 0.f};
#pragma unroll
        for (int kt = 0; kt < 8; ++kt) {
            bf16x8 bfr = *(const bf16x8*)(const void*)(Wk_sw + ((size_t)(ntg * 8 + kt) * 64 + lane) * 8);
            acc = __builtin_amdgcn_mfma_f32_16x16x32_bf16(afr[kt], bfr, acc, 0, 0, 0);
        }
        int col = ntg * 16 + lr;
#pragma unroll
        for (int rg = 0; rg < 4; ++rg)
            Kb[kbase + (size_t)(s0 + rg) * 256 + col] = (__hip_bfloat16)acc[rg];
    }
    for (int ntg = 0; ntg < 16; ++ntg) {
        f32x4 acc = {0.f, 0.f, 0.f, 0.f};
#pragma unroll
        for (int kt = 0; kt < 8; ++kt) {
            bf16x8 bfr = *(const bf16x8*)(const void*)(Wv_sw + ((size_t)(ntg * 8 + kt) * 64 + lane) * 8);
            acc = __builtin_amdgcn_mfma_f32_16x16x32_bf16(afr[kt], bfr, acc, 0, 0, 0);
        }
        int col = ntg * 16 + lr;
        __hip_bfloat16 t4[4];
#pragma unroll
        for (int rg = 0; rg < 4; ++rg) t4[rg] = (__hip_bfloat16)acc[rg];
        *(uint2*)(void*)(Vt + vtbase + (size_t)col * 64 + s0) = *(const uint2*)(const void*)t4;
    }
    if (node) {
        for (int ntg = 0; ntg < 16; ++ntg) {
            f32x4 acc = {0.f, 0.f, 0.f, 0.f};
#pragma unroll
            for (int kt = 0; kt < 8; ++kt) {
                bf16x8 bfr = *(const bf16x8*)(const void*)(wqb_sw + ((size_t)(ntg * 8 + kt) * 64 + lane) * 8);
                acc = __builtin_amdgcn_mfma_f32_16x16x32_bf16(afr[kt], bfr, acc, 0, 0, 0);
            }
            int col = ntg * 16 + lr;
#pragma unroll
            for (int rg = 0; rg < 4; ++rg)
                Qb[(size_t)(rb + s0 + rg) * 256 + col] = (__hip_bfloat16)acc[rg];
        }
    }
}

// ---------------------------------------------------------------------------
// Fused attention per (b,m), MFMA-based (validated).
// ---------------------------------------------------------------------------
__global__ __launch_bounds__(256) void attn_kernel(
    const __hip_bfloat16* __restrict__ Qb, const __hip_bfloat16* __restrict__ Kb,
    const __hip_bfloat16* __restrict__ Vt, const float* __restrict__ bbil,
    const float* __restrict__ Wprj, const float* __restrict__ bprj,
    float* __restrict__ A_out, float* __restrict__ out)
{
    __shared__ __align__(16) float Sbuf[64 * 68];
    __shared__ __align__(16) __hip_bfloat16 Pb[64 * 72];
    __shared__ float rowmax[64], rowrcp[64];
    __shared__ float red[64 * 16];
    const int tid = threadIdx.x;
    const int wave = tid >> 6, lane = tid & 63;
    const int quad = lane >> 4, lr = lane & 15;
    const int bm = blockIdx.x, b = bm / 17, m = bm % 17;
    const __hip_bfloat16* Qrow = Qb + (size_t)b * 64 * 256;
    const __hip_bfloat16* Krow = Kb + ((size_t)b * 1088 + m * 64) * 256;
    const __hip_bfloat16* Vtrow = Vt + (size_t)(b * 17 + m) * 256 * 64;

    f32x4 sacc[4] = {{0.f,0.f,0.f,0.f},{0.f,0.f,0.f,0.f},{0.f,0.f,0.f,0.f},{0.f,0.f,0.f,0.f}};
#pragma unroll
    for (int kt = 0; kt < 8; ++kt) {
        bf16x8 afr = *(const bf16x8*)(const void*)(Qrow + (size_t)(wave * 16 + lr) * 256 + kt * 32 + quad * 8);
#pragma unroll
        for (int c = 0; c < 4; ++c) {
            bf16x8 bfr = *(const bf16x8*)(const void*)(Krow + (size_t)(c * 16 + lr) * 256 + kt * 32 + quad * 8);
            sacc[c] = __builtin_amdgcn_mfma_f32_16x16x32_bf16(afr, bfr, sacc[c], 0, 0, 0);
        }
    }
#pragma unroll
    for (int c = 0; c < 4; ++c)
#pragma unroll
        for (int rg = 0; rg < 4; ++rg) {
            int t_ = wave * 16 + quad * 4 + rg, s_ = c * 16 + lr;
            Sbuf[t_ * 68 + s_] = (s_ <= t_) ? (sacc[c][rg] + bbil[s_]) : NEGV;
        }
    __syncthreads();
    if (tid < 64) {
        float mx = -3.0e38f;
        for (int s = 0; s < 64; ++s) mx = fmaxf(mx, Sbuf[tid * 68 + s]);
        float sum = 0.0f;
        for (int s = 0; s < 64; ++s) sum += __expf(Sbuf[tid * 68 + s] - mx);
        rowmax[tid] = mx;
        rowrcp[tid] = 1.0f / sum;
    }
    __syncthreads();
    for (int idx = tid; idx < 4096; idx += 256) {
        int t_ = idx >> 6, s_ = idx & 63;
        float e = __expf(Sbuf[t_ * 68 + s_] - rowmax[t_]) * rowrcp[t_];
        A_out[(size_t)bm * 4096 + idx] = e;
        Pb[t_ * 72 + s_] = (__hip_bfloat16)e;
    }
    __syncthreads();

    bf16x8 pfr[2];
#pragma unroll
    for (int k2 = 0; k2 < 2; ++k2)
        pfr[k2] = *(const bf16x8*)(const void*)(Pb + (wave * 16 + lr) * 72 + k2 * 32 + quad * 8);
    float part[4] = {0.f, 0.f, 0.f, 0.f};
#pragma unroll
    for (int nt = 0; nt < 16; ++nt) {
        f32x4 cacc = {0.f, 0.f, 0.f, 0.f};
#pragma unroll
        for (int k2 = 0; k2 < 2; ++k2) {
            bf16x8 bfr = *(const bf16x8*)(const void*)(Vtrow + (size_t)(nt * 16 + lr) * 64 + k2 * 32 + quad * 8);
            cacc = __builtin_amdgcn_mfma_f32_16x16x32_bf16(pfr[k2], bfr, cacc, 0, 0, 0);
        }
        float wp = Wprj[nt * 16 + lr];
#pragma unroll
        for (int rg = 0; rg < 4; ++rg) part[rg] += cacc[rg] * wp;
    }
#pragma unroll
    for (int rg = 0; rg < 4; ++rg) red[(wave * 16 + quad * 4 + rg) * 16 + lr] = part[rg];
    __syncthreads();
    if (tid < 64) {
        float s = 0.0f;
#pragma unroll
        for (int q = 0; q < 16; ++q) s += red[tid * 16 + q];
        if (m == 0) s += 17.0f * bprj[0];
        atomicAdd(out + b * 64 + tid, s);
    }
}

// ---------------------------------------------------------------------------
extern "C" void kernel_launch(void* const* d_in, const int* in_sizes, int n_in,
                              void* d_out, int out_size, void* d_ws, size_t ws_size,
                              hipStream_t stream)
{
    const float* node_input       = (const float*)d_in[0];
    const float* node_hidden      = (const float*)d_in[1];
    const float* neighbors_input  = (const float*)d_in[2];
    const float* neighbors_hidden = (const float*)d_in[3];
    const float* Wih_node = (const float*)d_in[5];
    const float* Whh_node = (const float*)d_in[6];
    const float* bih_node = (const float*)d_in[7];
    const float* bhh_node = (const float*)d_in[8];
    const float* Wih_ngh  = (const float*)d_in[9];
    const float* Whh_ngh  = (const float*)d_in[10];
    const float* bih_ngh  = (const float*)d_in[11];
    const float* bhh_ngh  = (const float*)d_in[12];
    const float* Wq   = (const float*)d_in[13];
    const float* Wk   = (const float*)d_in[14];
    const float* Wv   = (const float*)d_in[15];
    const float* Wbil = (const float*)d_in[16];
    const float* bbil = (const float*)d_in[17];
    const float* Wprj = (const float*)d_in[18];
    const float* bprj = (const float*)d_in[19];

    float* out         = (float*)d_out;          // (B,T)     4096
    float* out_node_hT = out + 4096;             // (1,B,H)   16384
    float* out_ngh_hT  = out + 20480;            // (1,B*N,H) 262144
    float* out_A       = out + 282624;           // (B,17,T,T)

    // ---- workspace layout (bytes) ----
    char* w = (char*)d_ws;
    float*          wqb_f    = (float*)(w);                      // 262144 B
    __hip_bfloat16* Wih_n_sw = (__hip_bfloat16*)(w + 262144);    // 196608
    __hip_bfloat16* Wih_g_sw = (__hip_bfloat16*)(w + 458752);    // 196608
    __hip_bfloat16* Whh_n_sw = (__hip_bfloat16*)(w + 655360);    // 393216
    __hip_bfloat16* Whh_g_sw = (__hip_bfloat16*)(w + 1048576);   // 393216
    __hip_bfloat16* Wk_sw    = (__hip_bfloat16*)(w + 1441792);   // 131072
    __hip_bfloat16* Wv_sw    = (__hip_bfloat16*)(w + 1572864);   // 131072
    __hip_bfloat16* wqb_sw   = (__hip_bfloat16*)(w + 1703936);   // 131072
    __hip_bfloat16* node_out_b = (__hip_bfloat16*)(w + 1835008); // 2097152
    __hip_bfloat16* ngh_out_b  = (__hip_bfloat16*)(w + 3932160); // 33554432
    __hip_bfloat16* qb_b       = (__hip_bfloat16*)(w + 37486592);// 2097152
    __hip_bfloat16* gi         = (__hip_bfloat16*)(w + 39583744);// 106954752
    __hip_bfloat16* kbuf = gi;                      // reuse gi region after scan
    __hip_bfloat16* vtbuf = kbuf + 17825792;        // 69632*256 each
    // end: 146538496 B

    hipMemsetAsync(d_out, 0, 4096 * sizeof(float), stream);

    wqb_gemm<<<dim3(4, 4), 256, 0, stream>>>(Wbil, Wq, wqb_f);

    convert_all<<<3072, 256, 0, stream>>>(
        Wih_node, Wih_ngh, Whh_node, Whh_ngh, Wk, Wv, wqb_f,
        Wih_n_sw, Wih_g_sw, Whh_n_sw, Whh_g_sw, Wk_sw, Wv_sw, wqb_sw);

    gi_gemm<<<1088, 256, 0, stream>>>(
        node_input, neighbors_input, Wih_n_sw, Wih_g_sw, bih_node, bih_ngh, gi);

    scan_kernel<<<68, 256, 0, stream>>>(gi, Whh_n_sw, Whh_g_sw,
        bhh_node, bhh_ngh, node_hidden, neighbors_hidden,
        node_out_b, ngh_out_b, out_node_hT, out_ngh_hT);

    kv_gemm<<<1088, 256, 0, stream>>>(
        node_out_b, ngh_out_b, Wk_sw, Wv_sw, wqb_sw, kbuf, vtbuf, qb_b);

    attn_kernel<<<1088, 256, 0, stream>>>(qb_b, kbuf, vtbuf, bbil, Wprj, bprj,
                                          out_A, out);
}

// Round 8
// 516.123 us; speedup vs baseline: 1.5222x; 1.5222x over previous
//
#include <hip/hip_runtime.h>
#include <hip/hip_bf16.h>

#define NEGV -1e30f
typedef __attribute__((ext_vector_type(8))) short bf16x8;
typedef __attribute__((ext_vector_type(4))) float f32x4;

__device__ __forceinline__ float sigmoidf_(float x) { return 1.0f / (1.0f + __expf(-x)); }
__device__ __forceinline__ float tanhf_(float x) {
    float ax = fabsf(x);
    float e = __expf(-2.0f * ax);
    float t = (1.0f - e) / (1.0f + e);
    return copysignf(t, x);
}
__device__ __forceinline__ float bf2f(unsigned short u) {
    union { float f; unsigned int i; } x; x.i = ((unsigned int)u) << 16; return x.f;
}

// ---------------------------------------------------------------------------
// wqb_t[h'][d] = sum_k Wbil[k][h'] * Wq[k][d]   (256x256 fp32)
// ---------------------------------------------------------------------------
__global__ __launch_bounds__(256) void wqb_gemm(const float* __restrict__ Wbil_,
    const float* __restrict__ Wq_, float* __restrict__ outw)
{
    __shared__ __align__(16) float As[32 * 68];
    __shared__ __align__(16) float Bs[32 * 68];
    const int tid = threadIdx.x, tx = tid & 15, ty = tid >> 4;
    const int rb = blockIdx.x * 64, cb = blockIdx.y * 64;
    float acc[4][4] = {};
    for (int k0 = 0; k0 < 256; k0 += 32) {
        __syncthreads();
        for (int f = tid; f < 2048; f += 256) {
            int kk = f >> 6, r = f & 63;
            As[kk * 68 + r] = Wbil_[(size_t)(k0 + kk) * 256 + rb + r];
        }
        for (int f = tid; f < 2048; f += 256) {
            int kk = f >> 6, c = f & 63;
            Bs[kk * 68 + c] = Wq_[(size_t)(k0 + kk) * 256 + cb + c];
        }
        __syncthreads();
#pragma unroll
        for (int kk = 0; kk < 32; ++kk) {
            float4 a4 = *(const float4*)(As + kk * 68 + ty * 4);
            float4 b4 = *(const float4*)(Bs + kk * 68 + tx * 4);
            float av[4] = {a4.x, a4.y, a4.z, a4.w};
            float bv[4] = {b4.x, b4.y, b4.z, b4.w};
#pragma unroll
            for (int i = 0; i < 4; ++i)
#pragma unroll
                for (int j = 0; j < 4; ++j) acc[i][j] += av[i] * bv[j];
        }
    }
#pragma unroll
    for (int i = 0; i < 4; ++i)
#pragma unroll
        for (int j = 0; j < 4; ++j)
            outw[(size_t)(rb + ty * 4 + i) * 256 + cb + tx * 4 + j] = acc[i][j];
}

// ---------------------------------------------------------------------------
// One-launch conversion of all weights to bf16 MFMA-B swizzled layout:
// (n,k) -> [((nt*(K/32)+kt)*64 + quad*16 + (n&15))*8 + (k&7)]
// ---------------------------------------------------------------------------
__device__ __forceinline__ void swz_store(const float* __restrict__ src,
    __hip_bfloat16* __restrict__ dst, int idx, int kshift)
{
    int n = idx >> kshift, k = idx & ((1 << kshift) - 1);
    int nt = n >> 4, kt = k >> 5, quad = (k & 31) >> 3, pos = k & 7;
    dst[((size_t)((nt << (kshift - 5)) + kt) * 64 + quad * 16 + (n & 15)) * 8 + pos] =
        (__hip_bfloat16)src[idx];
}

__global__ __launch_bounds__(256) void convert_all(
    const float* __restrict__ Wih_n, const float* __restrict__ Wih_g,
    const float* __restrict__ Whh_n, const float* __restrict__ Whh_g,
    const float* __restrict__ Wk_,   const float* __restrict__ Wv_,
    const float* __restrict__ wqb_f,
    __hip_bfloat16* Wih_n_sw, __hip_bfloat16* Wih_g_sw,
    __hip_bfloat16* Whh_n_sw, __hip_bfloat16* Whh_g_sw,
    __hip_bfloat16* Wk_sw, __hip_bfloat16* Wv_sw, __hip_bfloat16* wqb_sw)
{
    int g = blockIdx.x * 256 + threadIdx.x;
    if (g < 98304)        swz_store(Wih_n, Wih_n_sw, g, 7);
    else if (g < 196608)  swz_store(Wih_g, Wih_g_sw, g - 98304, 7);
    else if (g < 393216)  swz_store(Whh_n, Whh_n_sw, g - 196608, 8);
    else if (g < 589824)  swz_store(Whh_g, Whh_g_sw, g - 393216, 8);
    else if (g < 655360)  swz_store(Wk_,   Wk_sw,   g - 589824, 8);
    else if (g < 720896)  swz_store(Wv_,   Wv_sw,   g - 655360, 8);
    else                  swz_store(wqb_f, wqb_sw,  g - 720896, 8);
}

// ---------------------------------------------------------------------------
// gi = x @ Wih^T + bih, all 768 output cols per block (A staged once).
// ---------------------------------------------------------------------------
__global__ __launch_bounds__(256) void gi_gemm(
    const float* __restrict__ A0, const float* __restrict__ A1,
    const __hip_bfloat16* __restrict__ W0, const __hip_bfloat16* __restrict__ W1,
    const float* __restrict__ b0, const float* __restrict__ b1,
    __hip_bfloat16* __restrict__ C)
{
    __shared__ __align__(16) __hip_bfloat16 As[64 * 136];
    const int tid = threadIdx.x, wave = tid >> 6, lane = tid & 63;
    const int quad = lane >> 4, lr = lane & 15;
    const int rb = blockIdx.x * 64;
    const bool node = rb < 4096;
    const float* A = node ? (A0 + (size_t)rb * 128) : (A1 + (size_t)(rb - 4096) * 128);
    const __hip_bfloat16* W = node ? W0 : W1;
    const float* bias = node ? b0 : b1;

    for (int f = tid; f < 1024; f += 256) {
        int row = f >> 4, cc = (f & 15) * 8;
        const float* Af = A + (size_t)row * 128 + cc;
        float4 v0 = *(const float4*)Af;
        float4 v1 = *(const float4*)(Af + 4);
        __hip_bfloat16* d = As + row * 136 + cc;
        d[0] = (__hip_bfloat16)v0.x; d[1] = (__hip_bfloat16)v0.y;
        d[2] = (__hip_bfloat16)v0.z; d[3] = (__hip_bfloat16)v0.w;
        d[4] = (__hip_bfloat16)v1.x; d[5] = (__hip_bfloat16)v1.y;
        d[6] = (__hip_bfloat16)v1.z; d[7] = (__hip_bfloat16)v1.w;
    }
    __syncthreads();

    bf16x8 afr[4];
#pragma unroll
    for (int kt = 0; kt < 4; ++kt)
        afr[kt] = *(const bf16x8*)(const void*)(As + (wave * 16 + lr) * 136 + kt * 32 + quad * 8);

    const int r0 = rb + wave * 16 + quad * 4;
    for (int ntg = 0; ntg < 48; ++ntg) {
        f32x4 acc = {0.f, 0.f, 0.f, 0.f};
#pragma unroll
        for (int kt = 0; kt < 4; ++kt) {
            bf16x8 bfr = *(const bf16x8*)(const void*)(W + ((size_t)(ntg * 4 + kt) * 64 + lane) * 8);
            acc = __builtin_amdgcn_mfma_f32_16x16x32_bf16(afr[kt], bfr, acc, 0, 0, 0);
        }
        int col = ntg * 16 + lr;
        float bv = bias[col];
#pragma unroll
        for (int rg = 0; rg < 4; ++rg)
            C[(size_t)(r0 + rg) * 768 + col] = (__hip_bfloat16)(acc[rg] + bv);
    }
}

// ---------------------------------------------------------------------------
// Weight-stationary persistent GRU scan. 68 blocks x 512 threads (8 waves,
// 2 waves/SIMD). __launch_bounds__(512, 2) => VGPR cap 256/wave. Wave owns
// 6 n-tiles = 48 B-fragments = 192 VGPRs, loaded ONCE before the t-loop and
// held across all 64 steps (allocator-feasible: 192 + ~50 working < 256).
// Intrinsic MFMA only (compiler-managed hazards — the validated path).
// h master in LDS (saves regs); gi single-prefetch at loop top.
// ---------------------------------------------------------------------------
__global__ __launch_bounds__(512, 2) void scan_kernel(
    const __hip_bfloat16* __restrict__ gi,
    const __hip_bfloat16* __restrict__ Whh_n_sw,
    const __hip_bfloat16* __restrict__ Whh_g_sw,
    const float* __restrict__ bhh_node, const float* __restrict__ bhh_ngh,
    const float* __restrict__ node_hidden, const float* __restrict__ neighbors_hidden,
    __hip_bfloat16* __restrict__ node_out, __hip_bfloat16* __restrict__ ngh_out,
    float* __restrict__ out_node_hT, float* __restrict__ out_ngh_hT)
{
    __shared__ float h_f[16 * 257];
    __shared__ __align__(16) __hip_bfloat16 gh_b[16 * 776];
    __shared__ __align__(16) __hip_bfloat16 h_frag[8 * 64 * 8];
    __shared__ float bhh_l[768];
    const int tid = threadIdx.x;
    const int wave = tid >> 6, lane = tid & 63;
    const int quad = lane >> 4, lr = lane & 15;
    const int row0 = blockIdx.x * 16;
    const bool isnode = (row0 < 64);
    const __hip_bfloat16* Wsw = isnode ? Whh_n_sw : Whh_g_sw;
    const float* bhh = isnode ? bhh_node : bhh_ngh;
    const int pr = tid & 15;            // 0..15
    const int pc0 = (tid >> 4) * 8;     // 0..248
    const int grow = row0 + pr;
    const size_t gibase = isnode ? ((size_t)grow * 64) : (4096 + (size_t)(grow - 64) * 64);
    const int fragoff = ((pc0 >> 5) * 64 + ((pc0 & 31) >> 3) * 16 + pr) * 8;
    __hip_bfloat16* orow_base = isnode
        ? (node_out + ((size_t)grow * 64) * 256 + pc0)
        : (ngh_out + ((size_t)(grow - 64) * 64) * 256 + pc0);

    // ---- stationary weights: 48 fragments = 192 VGPRs/lane, held across t-loop
    bf16x8 wreg[48];
#pragma unroll
    for (int nt = 0; nt < 6; ++nt)
#pragma unroll
        for (int kt = 0; kt < 8; ++kt)
            wreg[nt * 8 + kt] = *(const bf16x8*)(const void*)(
                Wsw + ((size_t)((wave * 6 + nt) * 8 + kt) * 64 + lane) * 8);

    for (int f = tid; f < 768; f += 512) bhh_l[f] = bhh[f];

    // ---- h0 -> LDS fp32 master + bf16 fragment LDS
    {
        const float* src = isnode ? (node_hidden + (size_t)row0 * 256)
                                  : (neighbors_hidden + (size_t)(row0 - 64) * 256);
        const float* sp = src + (size_t)pr * 256 + pc0;
        float4 v0 = *(const float4*)(sp);
        float4 v1 = *(const float4*)(sp + 4);
        float vv[8] = {v0.x, v0.y, v0.z, v0.w, v1.x, v1.y, v1.z, v1.w};
        __hip_bfloat16 hb[8];
#pragma unroll
        for (int jj = 0; jj < 8; ++jj) {
            h_f[pr * 257 + pc0 + jj] = vv[jj];
            hb[jj] = (__hip_bfloat16)vv[jj];
        }
        *(uint4*)(void*)(h_frag + fragoff) = *(const uint4*)(const void*)hb;
    }
    __syncthreads();

#pragma unroll 1
    for (int t = 0; t < 64; ++t) {
        // gi prefetch: issued before the MFMA phase, consumed after the barrier
        const __hip_bfloat16* g = gi + (gibase + t) * 768 + pc0;
        bf16x8 g_r = *(const bf16x8*)(const void*)(g);
        bf16x8 g_z = *(const bf16x8*)(const void*)(g + 256);
        bf16x8 g_n = *(const bf16x8*)(const void*)(g + 512);

        // ---- MFMA: gh = h @ Whh^T, weights register-resident, zero traffic
        f32x4 acc[6] = {{0.f,0.f,0.f,0.f},{0.f,0.f,0.f,0.f},{0.f,0.f,0.f,0.f},
                        {0.f,0.f,0.f,0.f},{0.f,0.f,0.f,0.f},{0.f,0.f,0.f,0.f}};
#pragma unroll
        for (int kt = 0; kt < 8; ++kt) {
            bf16x8 afr = *(const bf16x8*)(const void*)(h_frag + (kt * 64 + lane) * 8);
#pragma unroll
            for (int nt = 0; nt < 6; ++nt)
                acc[nt] = __builtin_amdgcn_mfma_f32_16x16x32_bf16(afr, wreg[nt * 8 + kt], acc[nt], 0, 0, 0);
        }
#pragma unroll
        for (int nt = 0; nt < 6; ++nt) {
            int col = (wave * 6 + nt) * 16 + lr;
#pragma unroll
            for (int rg = 0; rg < 4; ++rg)
                gh_b[(quad * 4 + rg) * 776 + col] = (__hip_bfloat16)acc[nt][rg];
        }
        __syncthreads();

        // ---- pointwise gates: row pr, 8 cols
        {
            const __hip_bfloat16* ghrow = gh_b + pr * 776;
            bf16x8 Gr = *(const bf16x8*)(const void*)(ghrow + pc0);
            bf16x8 Gz = *(const bf16x8*)(const void*)(ghrow + 256 + pc0);
            bf16x8 Gn = *(const bf16x8*)(const void*)(ghrow + 512 + pc0);
            __hip_bfloat16 hb[8];
#pragma unroll
            for (int jj = 0; jj < 8; ++jj) {
                int j = pc0 + jj;
                float ghr = bf2f((unsigned short)Gr[jj]) + bhh_l[j];
                float ghz = bf2f((unsigned short)Gz[jj]) + bhh_l[256 + j];
                float ghn = bf2f((unsigned short)Gn[jj]) + bhh_l[512 + j];
                float rg_ = sigmoidf_(bf2f((unsigned short)g_r[jj]) + ghr);
                float zg  = sigmoidf_(bf2f((unsigned short)g_z[jj]) + ghz);
                float ng  = tanhf_(bf2f((unsigned short)g_n[jj]) + rg_ * ghn);
                float hp = h_f[pr * 257 + j];
                float hn = (1.0f - zg) * ng + zg * hp;
                h_f[pr * 257 + j] = hn;
                hb[jj] = (__hip_bfloat16)hn;
            }
            *(uint4*)(void*)(h_frag + fragoff) = *(const uint4*)(const void*)hb;
            __hip_bfloat16* orow = orow_base + (size_t)t * 256;
            *(uint4*)(void*)(orow) = *(const uint4*)(const void*)hb;
        }
        __syncthreads();
    }

    // ---- final hidden states fp32
    {
        float* dst = isnode ? (out_node_hT + (size_t)row0 * 256)
                            : (out_ngh_hT + (size_t)(row0 - 64) * 256);
        float v[8];
#pragma unroll
        for (int jj = 0; jj < 8; ++jj) v[jj] = h_f[pr * 257 + pc0 + jj];
        *(float4*)(dst + (size_t)pr * 256 + pc0)     = *(const float4*)v;
        *(float4*)(dst + (size_t)pr * 256 + pc0 + 4) = *(const float4*)(v + 4);
    }
}

// ---------------------------------------------------------------------------
// Fused K/V(+Qb for node rows) GEMM (validated).
// ---------------------------------------------------------------------------
__global__ __launch_bounds__(256) void kv_gemm(
    const __hip_bfloat16* __restrict__ A0, const __hip_bfloat16* __restrict__ A1,
    const __hip_bfloat16* __restrict__ Wk_sw, const __hip_bfloat16* __restrict__ Wv_sw,
    const __hip_bfloat16* __restrict__ wqb_sw,
    __hip_bfloat16* __restrict__ Kb, __hip_bfloat16* __restrict__ Vt,
    __hip_bfloat16* __restrict__ Qb)
{
    __shared__ __align__(16) __hip_bfloat16 As[64 * 264];
    const int tid = threadIdx.x, wave = tid >> 6, lane = tid & 63;
    const int quad = lane >> 4, lr = lane & 15;
    const int rb = blockIdx.x * 64;
    const bool node = rb < 4096;
    const __hip_bfloat16* A = node ? (A0 + (size_t)rb * 256) : (A1 + (size_t)(rb - 4096) * 256);

    for (int f = tid; f < 2048; f += 256) {
        int row = f >> 5, cc = (f & 31) * 8;
        *(uint4*)(void*)(As + row * 264 + cc) =
            *(const uint4*)(const void*)(A + (size_t)row * 256 + cc);
    }
    __syncthreads();

    bf16x8 afr[8];
#pragma unroll
    for (int kt = 0; kt < 8; ++kt)
        afr[kt] = *(const bf16x8*)(const void*)(As + (wave * 16 + lr) * 264 + kt * 32 + quad * 8);

    int b_, slot;
    if (node) { b_ = rb >> 6; slot = 0; }
    else { int rr = (rb - 4096) >> 6; b_ = rr >> 4; slot = (rr & 15) + 1; }
    const size_t kbase = ((size_t)b_ * 1088 + slot * 64) * 256;
    const size_t vtbase = (size_t)(b_ * 17 + slot) * 256 * 64;
    const int s0 = wave * 16 + quad * 4;

    for (int ntg = 0; ntg < 16; ++ntg) {
        f32x4 acc = {0.f, 0.f, 0.f, 0.f};
#pragma unroll
        for (int kt = 0; kt < 8; ++kt) {
            bf16x8 bfr = *(const bf16x8*)(const void*)(Wk_sw + ((size_t)(ntg * 8 + kt) * 64 + lane) * 8);
            acc = __builtin_amdgcn_mfma_f32_16x16x32_bf16(afr[kt], bfr, acc, 0, 0, 0);
        }
        int col = ntg * 16 + lr;
#pragma unroll
        for (int rg = 0; rg < 4; ++rg)
            Kb[kbase + (size_t)(s0 + rg) * 256 + col] = (__hip_bfloat16)acc[rg];
    }
    for (int ntg = 0; ntg < 16; ++ntg) {
        f32x4 acc = {0.f, 0.f, 0.f, 0.f};
#pragma unroll
        for (int kt = 0; kt < 8; ++kt) {
            bf16x8 bfr = *(const bf16x8*)(const void*)(Wv_sw + ((size_t)(ntg * 8 + kt) * 64 + lane) * 8);
            acc = __builtin_amdgcn_mfma_f32_16x16x32_bf16(afr[kt], bfr, acc, 0, 0, 0);
        }
        int col = ntg * 16 + lr;
        __hip_bfloat16 t4[4];
#pragma unroll
        for (int rg = 0; rg < 4; ++rg) t4[rg] = (__hip_bfloat16)acc[rg];
        *(uint2*)(void*)(Vt + vtbase + (size_t)col * 64 + s0) = *(const uint2*)(const void*)t4;
    }
    if (node) {
        for (int ntg = 0; ntg < 16; ++ntg) {
            f32x4 acc = {0.f, 0.f, 0.f, 0.f};
#pragma unroll
            for (int kt = 0; kt < 8; ++kt) {
                bf16x8 bfr = *(const bf16x8*)(const void*)(wqb_sw + ((size_t)(ntg * 8 + kt) * 64 + lane) * 8);
                acc = __builtin_amdgcn_mfma_f32_16x16x32_bf16(afr[kt], bfr, acc, 0, 0, 0);
            }
            int col = ntg * 16 + lr;
#pragma unroll
            for (int rg = 0; rg < 4; ++rg)
                Qb[(size_t)(rb + s0 + rg) * 256 + col] = (__hip_bfloat16)acc[rg];
        }
    }
}

// ---------------------------------------------------------------------------
// Fused attention per (b,m), MFMA-based (validated).
// ---------------------------------------------------------------------------
__global__ __launch_bounds__(256) void attn_kernel(
    const __hip_bfloat16* __restrict__ Qb, const __hip_bfloat16* __restrict__ Kb,
    const __hip_bfloat16* __restrict__ Vt, const float* __restrict__ bbil,
    const float* __restrict__ Wprj, const float* __restrict__ bprj,
    float* __restrict__ A_out, float* __restrict__ out)
{
    __shared__ __align__(16) float Sbuf[64 * 68];
    __shared__ __align__(16) __hip_bfloat16 Pb[64 * 72];
    __shared__ float rowmax[64], rowrcp[64];
    __shared__ float red[64 * 16];
    const int tid = threadIdx.x;
    const int wave = tid >> 6, lane = tid & 63;
    const int quad = lane >> 4, lr = lane & 15;
    const int bm = blockIdx.x, b = bm / 17, m = bm % 17;
    const __hip_bfloat16* Qrow = Qb + (size_t)b * 64 * 256;
    const __hip_bfloat16* Krow = Kb + ((size_t)b * 1088 + m * 64) * 256;
    const __hip_bfloat16* Vtrow = Vt + (size_t)(b * 17 + m) * 256 * 64;

    f32x4 sacc[4] = {{0.f,0.f,0.f,0.f},{0.f,0.f,0.f,0.f},{0.f,0.f,0.f,0.f},{0.f,0.f,0.f,0.f}};
#pragma unroll
    for (int kt = 0; kt < 8; ++kt) {
        bf16x8 afr = *(const bf16x8*)(const void*)(Qrow + (size_t)(wave * 16 + lr) * 256 + kt * 32 + quad * 8);
#pragma unroll
        for (int c = 0; c < 4; ++c) {
            bf16x8 bfr = *(const bf16x8*)(const void*)(Krow + (size_t)(c * 16 + lr) * 256 + kt * 32 + quad * 8);
            sacc[c] = __builtin_amdgcn_mfma_f32_16x16x32_bf16(afr, bfr, sacc[c], 0, 0, 0);
        }
    }
#pragma unroll
    for (int c = 0; c < 4; ++c)
#pragma unroll
        for (int rg = 0; rg < 4; ++rg) {
            int t_ = wave * 16 + quad * 4 + rg, s_ = c * 16 + lr;
            Sbuf[t_ * 68 + s_] = (s_ <= t_) ? (sacc[c][rg] + bbil[s_]) : NEGV;
        }
    __syncthreads();
    if (tid < 64) {
        float mx = -3.0e38f;
        for (int s = 0; s < 64; ++s) mx = fmaxf(mx, Sbuf[tid * 68 + s]);
        float sum = 0.0f;
        for (int s = 0; s < 64; ++s) sum += __expf(Sbuf[tid * 68 + s] - mx);
        rowmax[tid] = mx;
        rowrcp[tid] = 1.0f / sum;
    }
    __syncthreads();
    for (int idx = tid; idx < 4096; idx += 256) {
        int t_ = idx >> 6, s_ = idx & 63;
        float e = __expf(Sbuf[t_ * 68 + s_] - rowmax[t_]) * rowrcp[t_];
        A_out[(size_t)bm * 4096 + idx] = e;
        Pb[t_ * 72 + s_] = (__hip_bfloat16)e;
    }
    __syncthreads();

    bf16x8 pfr[2];
#pragma unroll
    for (int k2 = 0; k2 < 2; ++k2)
        pfr[k2] = *(const bf16x8*)(const void*)(Pb + (wave * 16 + lr) * 72 + k2 * 32 + quad * 8);
    float part[4] = {0.f, 0.f, 0.f, 0.f};
#pragma unroll
    for (int nt = 0; nt < 16; ++nt) {
        f32x4 cacc = {0.f, 0.f, 0.f, 0.f};
#pragma unroll
        for (int k2 = 0; k2 < 2; ++k2) {
            bf16x8 bfr = *(const bf16x8*)(const void*)(Vtrow + (size_t)(nt * 16 + lr) * 64 + k2 * 32 + quad * 8);
            cacc = __builtin_amdgcn_mfma_f32_16x16x32_bf16(pfr[k2], bfr, cacc, 0, 0, 0);
        }
        float wp = Wprj[nt * 16 + lr];
#pragma unroll
        for (int rg = 0; rg < 4; ++rg) part[rg] += cacc[rg] * wp;
    }
#pragma unroll
    for (int rg = 0; rg < 4; ++rg) red[(wave * 16 + quad * 4 + rg) * 16 + lr] = part[rg];
    __syncthreads();
    if (tid < 64) {
        float s = 0.0f;
#pragma unroll
        for (int q = 0; q < 16; ++q) s += red[tid * 16 + q];
        if (m == 0) s += 17.0f * bprj[0];
        atomicAdd(out + b * 64 + tid, s);
    }
}

// ---------------------------------------------------------------------------
extern "C" void kernel_launch(void* const* d_in, const int* in_sizes, int n_in,
                              void* d_out, int out_size, void* d_ws, size_t ws_size,
                              hipStream_t stream)
{
    const float* node_input       = (const float*)d_in[0];
    const float* node_hidden      = (const float*)d_in[1];
    const float* neighbors_input  = (const float*)d_in[2];
    const float* neighbors_hidden = (const float*)d_in[3];
    const float* Wih_node = (const float*)d_in[5];
    const float* Whh_node = (const float*)d_in[6];
    const float* bih_node = (const float*)d_in[7];
    const float* bhh_node = (const float*)d_in[8];
    const float* Wih_ngh  = (const float*)d_in[9];
    const float* Whh_ngh  = (const float*)d_in[10];
    const float* bih_ngh  = (const float*)d_in[11];
    const float* bhh_ngh  = (const float*)d_in[12];
    const float* Wq   = (const float*)d_in[13];
    const float* Wk   = (const float*)d_in[14];
    const float* Wv   = (const float*)d_in[15];
    const float* Wbil = (const float*)d_in[16];
    const float* bbil = (const float*)d_in[17];
    const float* Wprj = (const float*)d_in[18];
    const float* bprj = (const float*)d_in[19];

    float* out         = (float*)d_out;          // (B,T)     4096
    float* out_node_hT = out + 4096;             // (1,B,H)   16384
    float* out_ngh_hT  = out + 20480;            // (1,B*N,H) 262144
    float* out_A       = out + 282624;           // (B,17,T,T)

    // ---- workspace layout (bytes) ----
    char* w = (char*)d_ws;
    float*          wqb_f    = (float*)(w);                      // 262144 B
    __hip_bfloat16* Wih_n_sw = (__hip_bfloat16*)(w + 262144);    // 196608
    __hip_bfloat16* Wih_g_sw = (__hip_bfloat16*)(w + 458752);    // 196608
    __hip_bfloat16* Whh_n_sw = (__hip_bfloat16*)(w + 655360);    // 393216
    __hip_bfloat16* Whh_g_sw = (__hip_bfloat16*)(w + 1048576);   // 393216
    __hip_bfloat16* Wk_sw    = (__hip_bfloat16*)(w + 1441792);   // 131072
    __hip_bfloat16* Wv_sw    = (__hip_bfloat16*)(w + 1572864);   // 131072
    __hip_bfloat16* wqb_sw   = (__hip_bfloat16*)(w + 1703936);   // 131072
    __hip_bfloat16* node_out_b = (__hip_bfloat16*)(w + 1835008); // 2097152
    __hip_bfloat16* ngh_out_b  = (__hip_bfloat16*)(w + 3932160); // 33554432
    __hip_bfloat16* qb_b       = (__hip_bfloat16*)(w + 37486592);// 2097152
    __hip_bfloat16* gi         = (__hip_bfloat16*)(w + 39583744);// 106954752
    __hip_bfloat16* kbuf = gi;                      // reuse gi region after scan
    __hip_bfloat16* vtbuf = kbuf + 17825792;        // 69632*256 each
    // end: 146538496 B

    hipMemsetAsync(d_out, 0, 4096 * sizeof(float), stream);

    wqb_gemm<<<dim3(4, 4), 256, 0, stream>>>(Wbil, Wq, wqb_f);

    convert_all<<<3072, 256, 0, stream>>>(
        Wih_node, Wih_ngh, Whh_node, Whh_ngh, Wk, Wv, wqb_f,
        Wih_n_sw, Wih_g_sw, Whh_n_sw, Whh_g_sw, Wk_sw, Wv_sw, wqb_sw);

    gi_gemm<<<1088, 256, 0, stream>>>(
        node_input, neighbors_input, Wih_n_sw, Wih_g_sw, bih_node, bih_ngh, gi);

    scan_kernel<<<68, 512, 0, stream>>>(gi, Whh_n_sw, Whh_g_sw,
        bhh_node, bhh_ngh, node_hidden, neighbors_hidden,
        node_out_b, ngh_out_b, out_node_hT, out_ngh_hT);

    kv_gemm<<<1088, 256, 0, stream>>>(
        node_out_b, ngh_out_b, Wk_sw, Wv_sw, wqb_sw, kbuf, vtbuf, qb_b);

    attn_kernel<<<1088, 256, 0, stream>>>(qb_b, kbuf, vtbuf, bbil, Wprj, bprj,
                                          out_A, out);
}